// Round 5
// baseline (2460.138 us; speedup 1.0000x reference)
//
#include <hip/hip_runtime.h>
#include <hip/hip_bf16.h>

#define HN 128        // rnn_size
#define TT 2048       // time steps
#define BATCH 64
#define G3 384        // 3*H
#define NT 512        // 8 waves
#define CH 16         // chains (batches of one direction) per block
#define PUS 296       // Hb row pitch in ushorts (592B; 148 words -> 2-way max on frag reads)

typedef float f32x4 __attribute__((ext_vector_type(4)));
typedef short s16x8 __attribute__((ext_vector_type(8)));

__device__ __forceinline__ ushort f2bf(float f) {   // RNE float->bf16
  unsigned u = __float_as_uint(f);
  unsigned r = (u + 0x7FFFu + ((u >> 16) & 1u)) >> 16;
  return (ushort)r;
}
__device__ __forceinline__ float bf2f(ushort s) {
  return __uint_as_float(((unsigned)s) << 16);
}
__device__ __forceinline__ float fast_sigmoid(float x) {
  float e = __builtin_amdgcn_exp2f(-x * 1.44269504088896340736f);
  return __builtin_amdgcn_rcpf(1.0f + e);
}
__device__ __forceinline__ float fast_tanh(float x) {
  float e = __builtin_amdgcn_exp2f(x * 2.88539008177792681472f);
  return 1.0f - 2.0f * __builtin_amdgcn_rcpf(e + 1.0f);
}

#define MFMA(A, B, C) __builtin_amdgcn_mfma_f32_16x16x32_bf16((A), (B), (C), 0, 0, 0)

// K-stack layout per chain row c in LDS (ushort positions):
//   [0,128)   h_hi      (pairs with Wh_hi and Wh_lo B-frags)
//   [128,256) h_lo      (pairs with Wh_hi)
//   [256,264) x_hi      (pairs with Wi_hi)
//   [264,272) x_lo      (pairs with Wi_hi)
//   [272,280) x_hi dup  (pairs with Wi_lo)
//   [280,288) zero
// 8 blocks: blk&1 = direction, (blk>>1)*16 = batch group. 8 waves; wave w owns
// output columns j in [16w, 16w+16) for all three gates. C layout (m89):
// col=lane&15 (j), row=(lane>>4)*4+reg (chain). h state lives per-lane in
// registers AND is re-broadcast via LDS bf16 hi/lo planes each step.
__global__ __launch_bounds__(NT, 2) void gru_mfma_kernel(
    const float* __restrict__ y, const float* __restrict__ u,
    const float* __restrict__ Wi_f, const float* __restrict__ bi_f,
    const float* __restrict__ Wh_f, const float* __restrict__ bhn_f,
    const float* __restrict__ Wi_b, const float* __restrict__ bi_b,
    const float* __restrict__ Wh_b, const float* __restrict__ bhn_b,
    float* __restrict__ feat)
{
  const int blk    = blockIdx.x;
  const int dir    = blk & 1;
  const int batch0 = (blk >> 1) * CH;
  const float* __restrict__ Wi  = dir ? Wi_b  : Wi_f;
  const float* __restrict__ bi  = dir ? bi_b  : bi_f;
  const float* __restrict__ Wh  = dir ? Wh_b  : Wh_f;
  const float* __restrict__ bhn = dir ? bhn_b : bhn_f;

  const int tid  = threadIdx.x;
  const int lane = tid & 63;
  const int wv   = tid >> 6;      // 0..7
  const int ln15 = lane & 15;
  const int g4   = lane >> 4;     // 0..3
  const int j    = wv * 16 + ln15;

  __shared__ __align__(16) ushort Hb[2][CH][PUS];

  // ---- zero both buffers ----
  for (int i = tid; i < 2 * CH * PUS / 2; i += NT) ((unsigned*)Hb)[i] = 0;

  // ---- resident B-frags: BH/BL[gate][ktile], BX[gate] ----
  s16x8 BH[3][4], BL[3][4], BX[3];
  #pragma unroll
  for (int gi = 0; gi < 3; ++gi) {
    const int col = gi * 128 + j;
    #pragma unroll
    for (int kt = 0; kt < 4; ++kt) {
      s16x8 bh_, bl_;
      #pragma unroll
      for (int e = 0; e < 8; ++e) {
        const int row = kt * 32 + g4 * 8 + e;
        const float v = Wh[row * G3 + col];
        const ushort hi = f2bf(v);
        bh_[e] = (short)hi;
        bl_[e] = (short)f2bf(v - bf2f(hi));
      }
      BH[gi][kt] = bh_;
      BL[gi][kt] = bl_;
    }
    s16x8 bx_;
    #pragma unroll
    for (int e = 0; e < 8; ++e) {
      const int kl = g4 * 8 + e;
      ushort us = 0;
      if (kl < 8) {                       // pairs with x_hi
        us = f2bf(Wi[kl * G3 + col]);
      } else if (kl < 16) {               // pairs with x_lo -> Wi_hi
        us = f2bf(Wi[(kl - 8) * G3 + col]);
      } else if (kl < 24) {               // pairs with x_hi dup -> Wi_lo
        const float v = Wi[(kl - 16) * G3 + col];
        const ushort hi = f2bf(v);
        us = f2bf(v - bf2f(hi));
      }
      bx_[e] = (short)us;
    }
    BX[gi] = bx_;
  }

  // biases for this lane's column j
  const float bir = bi[j], biz = bi[128 + j], bin = bi[256 + j], bh = bhn[j];

  // writer-lane setup (wave 0): lane -> (chain c_w, dim-pair dp)
  const int c_w = lane >> 2;
  const int dp  = lane & 3;
  const float* __restrict__ xbase = (dp < 2) ? y : u;
  const size_t xrow = (size_t)(batch0 + c_w) * TT;
  const int xoff = (dp & 1) * 2;

  __syncthreads();  // zero-init visible before x(0) staging

  // ---- stage x(t=0) into Hb[0] ----
  if (wv == 0) {
    const int te = dir ? (TT - 1) : 0;
    const float2 xv = *(const float2*)(xbase + (xrow + te) * 4 + xoff);
    const ushort h0 = f2bf(xv.x), h1 = f2bf(xv.y);
    const ushort l0 = f2bf(xv.x - bf2f(h0)), l1 = f2bf(xv.y - bf2f(h1));
    const unsigned hi01 = (unsigned)h0 | ((unsigned)h1 << 16);
    const unsigned lo01 = (unsigned)l0 | ((unsigned)l1 << 16);
    unsigned* rw = (unsigned*)&Hb[0][c_w][0];
    rw[128 + dp] = hi01;   // ushort pos 256+2dp
    rw[132 + dp] = lo01;   // pos 264+2dp
    rw[136 + dp] = hi01;   // pos 272+2dp (dup for Wi_lo term)
  }

  float  hprev[4] = {0.f, 0.f, 0.f, 0.f};
  double hs[4]    = {0.0, 0.0, 0.0, 0.0};
  __syncthreads();

  int cur = 0;
  for (int t = 0; t < TT; ++t) {
    // ---- writer: issue next-step x loads early (latency hides under MFMA) ----
    float2 xv;
    if (wv == 0) {
      const int tn = (t + 1 < TT) ? (t + 1) : (TT - 1);
      const int te = dir ? (TT - 1 - tn) : tn;
      xv = *(const float2*)(xbase + (xrow + te) * 4 + xoff);
    }

    const ushort* rowp = &Hb[cur][ln15][0];
    const int fo = g4 * 8;

    // ---- hi A-frags + x frag ----
    const s16x8 aH0 = *(const s16x8*)(rowp + 0   + fo);
    const s16x8 aH1 = *(const s16x8*)(rowp + 32  + fo);
    const s16x8 aH2 = *(const s16x8*)(rowp + 64  + fo);
    const s16x8 aH3 = *(const s16x8*)(rowp + 96  + fo);
    const s16x8 aX  = *(const s16x8*)(rowp + 256 + fo);

    f32x4 Cr = {0.f, 0.f, 0.f, 0.f};
    f32x4 Cz = {0.f, 0.f, 0.f, 0.f};
    f32x4 Cn = {0.f, 0.f, 0.f, 0.f};
    f32x4 Cx = {0.f, 0.f, 0.f, 0.f};

    // h_hi * Wh_hi
    Cr = MFMA(aH0, BH[0][0], Cr); Cz = MFMA(aH0, BH[1][0], Cz); Cn = MFMA(aH0, BH[2][0], Cn);
    Cr = MFMA(aH1, BH[0][1], Cr); Cz = MFMA(aH1, BH[1][1], Cz); Cn = MFMA(aH1, BH[2][1], Cn);
    Cr = MFMA(aH2, BH[0][2], Cr); Cz = MFMA(aH2, BH[1][2], Cz); Cn = MFMA(aH2, BH[2][2], Cn);
    Cr = MFMA(aH3, BH[0][3], Cr); Cz = MFMA(aH3, BH[1][3], Cz); Cn = MFMA(aH3, BH[2][3], Cn);
    // h_hi * Wh_lo
    Cr = MFMA(aH0, BL[0][0], Cr); Cz = MFMA(aH0, BL[1][0], Cz); Cn = MFMA(aH0, BL[2][0], Cn);
    Cr = MFMA(aH1, BL[0][1], Cr); Cz = MFMA(aH1, BL[1][1], Cz); Cn = MFMA(aH1, BL[2][1], Cn);
    Cr = MFMA(aH2, BL[0][2], Cr); Cz = MFMA(aH2, BL[1][2], Cz); Cn = MFMA(aH2, BL[2][2], Cn);
    Cr = MFMA(aH3, BL[0][3], Cr); Cz = MFMA(aH3, BL[1][3], Cz); Cn = MFMA(aH3, BL[2][3], Cn);
    // x terms (Cx kept separate: n-gate xw must stay outside r*(...))
    Cr = MFMA(aX, BX[0], Cr); Cz = MFMA(aX, BX[1], Cz); Cx = MFMA(aX, BX[2], Cx);

    // ---- lo A-frags ----
    const s16x8 aL0 = *(const s16x8*)(rowp + 128 + fo);
    const s16x8 aL1 = *(const s16x8*)(rowp + 160 + fo);
    const s16x8 aL2 = *(const s16x8*)(rowp + 192 + fo);
    const s16x8 aL3 = *(const s16x8*)(rowp + 224 + fo);
    // h_lo * Wh_hi
    Cr = MFMA(aL0, BH[0][0], Cr); Cz = MFMA(aL0, BH[1][0], Cz); Cn = MFMA(aL0, BH[2][0], Cn);
    Cr = MFMA(aL1, BH[0][1], Cr); Cz = MFMA(aL1, BH[1][1], Cz); Cn = MFMA(aL1, BH[2][1], Cn);
    Cr = MFMA(aL2, BH[0][2], Cr); Cz = MFMA(aL2, BH[1][2], Cz); Cn = MFMA(aL2, BH[2][2], Cn);
    Cr = MFMA(aL3, BH[0][3], Cr); Cz = MFMA(aL3, BH[1][3], Cz); Cn = MFMA(aL3, BH[2][3], Cn);

    // ---- writer: split & store x(t+1) into next buffer ----
    if (wv == 0) {
      const ushort h0 = f2bf(xv.x), h1 = f2bf(xv.y);
      const ushort l0 = f2bf(xv.x - bf2f(h0)), l1 = f2bf(xv.y - bf2f(h1));
      const unsigned hi01 = (unsigned)h0 | ((unsigned)h1 << 16);
      const unsigned lo01 = (unsigned)l0 | ((unsigned)l1 << 16);
      unsigned* rw = (unsigned*)&Hb[cur ^ 1][c_w][0];
      rw[128 + dp] = hi01;
      rw[132 + dp] = lo01;
      rw[136 + dp] = hi01;
    }

    // ---- gates: lane holds (chain c = g4*4+i, column j) ----
    #pragma unroll
    for (int i = 0; i < 4; ++i) {
      const float r = fast_sigmoid(Cr[i] + bir);
      const float z = fast_sigmoid(Cz[i] + biz);
      const float n = fast_tanh((Cx[i] + bin) + r * (Cn[i] + bh));
      const float h = fmaf(z, hprev[i] - n, n);
      hprev[i] = h;
      hs[i] += (double)h;
      const ushort hi = f2bf(h);
      const ushort lo = f2bf(h - bf2f(hi));
      const int c = g4 * 4 + i;
      Hb[cur ^ 1][c][j]        = hi;
      Hb[cur ^ 1][c][128 + j]  = lo;
    }
    __syncthreads();
    cur ^= 1;
  }

  #pragma unroll
  for (int i = 0; i < 4; ++i) {
    const int c = g4 * 4 + i;
    feat[(size_t)(batch0 + c) * 256 + dir * HN + j] = (float)(hs[i] * (1.0 / TT));
  }
}

// ---- tiny MLP heads: feat[64,256] -> (m[64,20], s[64,20]) ----
__global__ __launch_bounds__(128) void mlp_kernel(
    const float* __restrict__ feat,
    const float* __restrict__ mW0, const float* __restrict__ mb0,
    const float* __restrict__ mW1, const float* __restrict__ mb1,
    const float* __restrict__ mW2, const float* __restrict__ mb2,
    const float* __restrict__ sW0, const float* __restrict__ sb0,
    const float* __restrict__ sW1, const float* __restrict__ sb1,
    const float* __restrict__ sW2, const float* __restrict__ sb2,
    float* __restrict__ out)
{
  const int b = blockIdx.x;
  const int tid = threadIdx.x;
  __shared__ float f[256];
  __shared__ float h1[128];
  __shared__ float h2[64];

  f[tid]       = feat[b * 256 + tid];
  f[tid + 128] = feat[b * 256 + 128 + tid];
  __syncthreads();

  for (int head = 0; head < 2; ++head) {
    const float* __restrict__ W0 = head ? sW0 : mW0;
    const float* __restrict__ b0 = head ? sb0 : mb0;
    const float* __restrict__ W1 = head ? sW1 : mW1;
    const float* __restrict__ b1 = head ? sb1 : mb1;
    const float* __restrict__ W2 = head ? sW2 : mW2;
    const float* __restrict__ b2 = head ? sb2 : mb2;

    float a = b0[tid];
    for (int k = 0; k < 256; ++k) a = fmaf(f[k], W0[k * 128 + tid], a);
    h1[tid] = fast_tanh(a);
    __syncthreads();

    if (tid < 64) {
      float a1 = b1[tid];
      for (int k = 0; k < 128; ++k) a1 = fmaf(h1[k], W1[k * 64 + tid], a1);
      h2[tid] = fast_tanh(a1);
    }
    __syncthreads();

    if (tid < 20) {
      float a2 = b2[tid];
      for (int k = 0; k < 64; ++k) a2 = fmaf(h2[k], W2[k * 20 + tid], a2);
      out[head * (BATCH * 20) + b * 20 + tid] = a2;
    }
    __syncthreads();
  }
}

extern "C" void kernel_launch(void* const* d_in, const int* in_sizes, int n_in,
                              void* d_out, int out_size, void* d_ws, size_t ws_size,
                              hipStream_t stream) {
  const float* y     = (const float*)d_in[0];
  const float* u     = (const float*)d_in[1];
  const float* Wi_f  = (const float*)d_in[2];
  const float* bi_f  = (const float*)d_in[3];
  const float* Wh_f  = (const float*)d_in[4];
  const float* bhn_f = (const float*)d_in[5];
  const float* Wi_b  = (const float*)d_in[6];
  const float* bi_b  = (const float*)d_in[7];
  const float* Wh_b  = (const float*)d_in[8];
  const float* bhn_b = (const float*)d_in[9];
  const float* mW0 = (const float*)d_in[10]; const float* mb0 = (const float*)d_in[11];
  const float* mW1 = (const float*)d_in[12]; const float* mb1 = (const float*)d_in[13];
  const float* mW2 = (const float*)d_in[14]; const float* mb2 = (const float*)d_in[15];
  const float* sW0 = (const float*)d_in[16]; const float* sb0 = (const float*)d_in[17];
  const float* sW1 = (const float*)d_in[18]; const float* sb1 = (const float*)d_in[19];
  const float* sW2 = (const float*)d_in[20]; const float* sb2 = (const float*)d_in[21];

  float* feat = (float*)d_ws;  // [64, 256]
  float* out  = (float*)d_out; // m[64,20] then s[64,20]

  gru_mfma_kernel<<<8, NT, 0, stream>>>(
      y, u, Wi_f, bi_f, Wh_f, bhn_f, Wi_b, bi_b, Wh_b, bhn_b, feat);
  mlp_kernel<<<BATCH, 128, 0, stream>>>(
      feat, mW0, mb0, mW1, mb1, mW2, mb2, sW0, sb0, sW1, sb1, sW2, sb2, out);
}

// Round 6
// 1205.444 us; speedup vs baseline: 2.0409x; 2.0409x over previous
//
#include <hip/hip_runtime.h>
#include <hip/hip_bf16.h>

#define HN 128        // rnn_size
#define TT 2048       // time steps
#define BATCH 64
#define G3 384        // 3*H
#define NT 512        // 64 jp-groups x 8 k-slices
#define PITCH 148     // replica pitch (floats): read addr = p*(148+16) = p*164; 164%32=4
                      // -> replica-p b128 reads start at bank 4p: zero conflicts.

typedef float f32x2 __attribute__((ext_vector_type(2)));
typedef float f32x4 __attribute__((ext_vector_type(4)));

__device__ __forceinline__ f32x2 fma2(f32x2 a, f32x2 b, f32x2 c) {
#if __has_builtin(__builtin_elementwise_fma)
  return __builtin_elementwise_fma(a, b, c);   // -> v_pk_fma_f32
#else
  f32x2 r; r[0] = fmaf(a[0], b[0], c[0]); r[1] = fmaf(a[1], b[1], c[1]); return r;
#endif
}
__device__ __forceinline__ f32x2 lo2(f32x4 v) { return __builtin_shufflevector(v, v, 0, 1); }
__device__ __forceinline__ f32x2 hi2(f32x4 v) { return __builtin_shufflevector(v, v, 2, 3); }

__device__ __forceinline__ float fast_sigmoid(float x) {
  float e = __builtin_amdgcn_exp2f(-x * 1.44269504088896340736f);
  return __builtin_amdgcn_rcpf(1.0f + e);
}
__device__ __forceinline__ float fast_tanh(float x) {
  float e = __builtin_amdgcn_exp2f(x * 2.88539008177792681472f);
  return 1.0f - 2.0f * __builtin_amdgcn_rcpf(e + 1.0f);
}
// DPP butterfly over 8-lane groups (p = lane&7): ^1, ^2, ^7 (half mirror).
__device__ __forceinline__ float dpp_add(float v, int ctrl_sel) {
  int x = __float_as_int(v);
  int y;
  if (ctrl_sel == 0)      y = __builtin_amdgcn_mov_dpp(x, 0xB1, 0xF, 0xF, true);  // lane^1
  else if (ctrl_sel == 1) y = __builtin_amdgcn_mov_dpp(x, 0x4E, 0xF, 0xF, true);  // lane^2
  else                    y = __builtin_amdgcn_mov_dpp(x, 0x141, 0xF, 0xF, true); // lane^7
  return v + __int_as_float(y);
}

// One block per (batch, direction): 128 blocks, 1/CU. Thread (jp, p):
// jp = tid>>3 in [0,64), p = tid&7 owns k in [16p,16p+16) and input dim d=p.
// 6 column partials {r,z,n} x {jA=jp, jB=jp+64} via packed f32x2 FMAs over
// k-pairs; 8-lane all-DPP reduce; each lane finalizes one j-half and writes h
// to 2 of 8 replicas (bank-permutation-matched so reads are conflict-free).
__global__ __launch_bounds__(NT, 2) void gru_scan_kernel(
    const float* __restrict__ y, const float* __restrict__ u,
    const float* __restrict__ Wi_f, const float* __restrict__ bi_f,
    const float* __restrict__ Wh_f, const float* __restrict__ bhn_f,
    const float* __restrict__ Wi_b, const float* __restrict__ bi_b,
    const float* __restrict__ Wh_b, const float* __restrict__ bhn_b,
    float* __restrict__ feat)
{
  const int b   = blockIdx.x >> 1;
  const int dir = blockIdx.x & 1;
  const float* __restrict__ Wi  = dir ? Wi_b  : Wi_f;
  const float* __restrict__ bi  = dir ? bi_b  : bi_f;
  const float* __restrict__ Wh  = dir ? Wh_b  : Wh_f;
  const float* __restrict__ bhn = dir ? bhn_b : bhn_f;

  const int tid = threadIdx.x;
  const int p   = tid & 7;       // k-slice AND input dim
  const int jp  = tid >> 3;      // 0..63
  const bool hiHalf = (p >= 4);
  const int jw  = jp + (hiHalf ? 64 : 0);   // the j this lane finalizes
  const int k0  = p * 16;
  const int r1  = (5 * p) & 7;   // write replicas (bank-permutation inverse)
  const int r2  = r1 ^ 4;

  __shared__ float4 y_lds[TT];            // 32 KB
  __shared__ float4 u_lds[TT];            // 32 KB
  __shared__ float  h_rep[2][8][PITCH];   // double-buffered, 8 replicas

  // ---- stage y/u (coalesced float4) ----
  const float4* yg = reinterpret_cast<const float4*>(y) + (size_t)b * TT;
  const float4* ug = reinterpret_cast<const float4*>(u) + (size_t)b * TT;
  for (int idx = tid; idx < TT; idx += NT) {
    y_lds[idx] = yg[idx];
    u_lds[idx] = ug[idx];
  }
  // ---- zero h buffers ----
  for (int i = tid; i < 2 * 8 * PITCH; i += NT) ((float*)h_rep)[i] = 0.f;

  // ---- resident Wh k-pair tile: wA/wB[qp][g] = {Wh[k0+2qp][col], Wh[k0+2qp+1][col]} ----
  f32x2 wA[8][3], wB[8][3];
  #pragma unroll
  for (int qp = 0; qp < 8; ++qp) {
    const size_t r0 = (size_t)(k0 + 2 * qp) * G3;
    const size_t r1_ = r0 + G3;
    #pragma unroll
    for (int g = 0; g < 3; ++g) {
      wA[qp][g] = f32x2{Wh[r0 + g * 128 + jp],      Wh[r1_ + g * 128 + jp]};
      wB[qp][g] = f32x2{Wh[r0 + g * 128 + 64 + jp], Wh[r1_ + g * 128 + 64 + jp]};
    }
  }

  // input-proj weights for dim d=p, both j-halves
  const float wirA = Wi[p * G3 + jp],       wirB = Wi[p * G3 + 64 + jp];
  const float wizA = Wi[p * G3 + 128 + jp], wizB = Wi[p * G3 + 192 + jp];
  const float winA = Wi[p * G3 + 256 + jp], winB = Wi[p * G3 + 320 + jp];
  // biases pre-scaled by 1/8 (8 lanes each contribute once; butterfly sums them)
  const float birA8 = 0.125f * bi[jp],        birB8 = 0.125f * bi[64 + jp];
  const float bizA8 = 0.125f * bi[128 + jp],  bizB8 = 0.125f * bi[192 + jp];
  const float binA8 = 0.125f * bi[256 + jp],  binB8 = 0.125f * bi[320 + jp];
  const float bhA8  = 0.125f * bhn[jp],       bhB8  = 0.125f * bhn[64 + jp];

  // per-step x[p] broadcast source
  const float* yf = reinterpret_cast<const float*>(y_lds);
  const float* uf = reinterpret_cast<const float*>(u_lds);
  const float* xsrc = (p < 4) ? (yf + p) : (uf + p - 4);

  float h = 0.f;
  double hsum = 0.0;
  __syncthreads();

  const int dte = dir ? -1 : 1;
  int te = dir ? (TT - 1) : 0;
  int cur = 0;

  for (int t = 0; t < TT; ++t, te += dte) {
    // ---- conflict-free h reads: replica p, slice k0 (banks 4p..4p+3) ----
    const f32x4* hp4 = reinterpret_cast<const f32x4*>(&h_rep[cur][p][k0]);
    const f32x4 h0v = hp4[0], h1v = hp4[1], h2v = hp4[2], h3v = hp4[3];

    f32x2 Ar = {birA8, 0.f}, Az = {bizA8, 0.f}, An = {bhA8, 0.f};
    f32x2 Br = {birB8, 0.f}, Bz = {bizB8, 0.f}, Bn = {bhB8, 0.f};

    const f32x2 hq[8] = {lo2(h0v), hi2(h0v), lo2(h1v), hi2(h1v),
                         lo2(h2v), hi2(h2v), lo2(h3v), hi2(h3v)};
    #pragma unroll
    for (int qp = 0; qp < 8; ++qp) {
      const f32x2 hh = hq[qp];
      Ar = fma2(hh, wA[qp][0], Ar);
      Az = fma2(hh, wA[qp][1], Az);
      An = fma2(hh, wA[qp][2], An);
      Br = fma2(hh, wB[qp][0], Br);
      Bz = fma2(hh, wB[qp][1], Bz);
      Bn = fma2(hh, wB[qp][2], Bn);
    }

    // ---- fold distributed x-proj, collapse pairs ----
    const float xk = xsrc[te * 4];
    float arA = fmaf(xk, wirA, Ar[0] + Ar[1]);
    float azA = fmaf(xk, wizA, Az[0] + Az[1]);
    float anA = An[0] + An[1];
    float axA = fmaf(xk, winA, binA8);
    float arB = fmaf(xk, wirB, Br[0] + Br[1]);
    float azB = fmaf(xk, wizB, Bz[0] + Bz[1]);
    float anB = Bn[0] + Bn[1];
    float axB = fmaf(xk, winB, binB8);

    // ---- 8-lane all-DPP butterfly (3 stages, 8 values) ----
    arA = dpp_add(arA, 0); azA = dpp_add(azA, 0); anA = dpp_add(anA, 0); axA = dpp_add(axA, 0);
    arB = dpp_add(arB, 0); azB = dpp_add(azB, 0); anB = dpp_add(anB, 0); axB = dpp_add(axB, 0);
    arA = dpp_add(arA, 1); azA = dpp_add(azA, 1); anA = dpp_add(anA, 1); axA = dpp_add(axA, 1);
    arB = dpp_add(arB, 1); azB = dpp_add(azB, 1); anB = dpp_add(anB, 1); axB = dpp_add(axB, 1);
    arA = dpp_add(arA, 2); azA = dpp_add(azA, 2); anA = dpp_add(anA, 2); axA = dpp_add(axA, 2);
    arB = dpp_add(arB, 2); azB = dpp_add(azB, 2); anB = dpp_add(anB, 2); axB = dpp_add(axB, 2);

    // ---- select this lane's j-half, gates once ----
    const float ar = hiHalf ? arB : arA;
    const float az = hiHalf ? azB : azA;
    const float an = hiHalf ? anB : anA;
    const float ax = hiHalf ? axB : axA;

    const float r = fast_sigmoid(ar);
    const float z = fast_sigmoid(az);
    const float n = fast_tanh(ax + r * an);   // tanh(xw_n + bin + r*(hp_n + bhn))
    h = fmaf(z, h - n, n);                    // (1-z)*n + z*h
    hsum += (double)h;

    // ---- write h to replicas r1, r2 (each ds_write_b32 exactly 2-way) ----
    h_rep[cur ^ 1][r1][jw] = h;
    h_rep[cur ^ 1][r2][jw] = h;
    __syncthreads();
    cur ^= 1;
  }

  if (p == 0 || p == 4) {
    feat[(size_t)b * 256 + dir * HN + jw] = (float)(hsum * (1.0 / TT));
  }
}

// ---- tiny MLP heads: feat[64,256] -> (m[64,20], s[64,20]) ----
__global__ __launch_bounds__(128) void mlp_kernel(
    const float* __restrict__ feat,
    const float* __restrict__ mW0, const float* __restrict__ mb0,
    const float* __restrict__ mW1, const float* __restrict__ mb1,
    const float* __restrict__ mW2, const float* __restrict__ mb2,
    const float* __restrict__ sW0, const float* __restrict__ sb0,
    const float* __restrict__ sW1, const float* __restrict__ sb1,
    const float* __restrict__ sW2, const float* __restrict__ sb2,
    float* __restrict__ out)
{
  const int b = blockIdx.x;
  const int tid = threadIdx.x;
  __shared__ float f[256];
  __shared__ float h1[128];
  __shared__ float h2[64];

  f[tid]       = feat[b * 256 + tid];
  f[tid + 128] = feat[b * 256 + 128 + tid];
  __syncthreads();

  for (int head = 0; head < 2; ++head) {
    const float* __restrict__ W0 = head ? sW0 : mW0;
    const float* __restrict__ b0 = head ? sb0 : mb0;
    const float* __restrict__ W1 = head ? sW1 : mW1;
    const float* __restrict__ b1 = head ? sb1 : mb1;
    const float* __restrict__ W2 = head ? sW2 : mW2;
    const float* __restrict__ b2 = head ? sb2 : mb2;

    float a = b0[tid];
    for (int k = 0; k < 256; ++k) a = fmaf(f[k], W0[k * 128 + tid], a);
    h1[tid] = fast_tanh(a);
    __syncthreads();

    if (tid < 64) {
      float a1 = b1[tid];
      for (int k = 0; k < 128; ++k) a1 = fmaf(h1[k], W1[k * 64 + tid], a1);
      h2[tid] = fast_tanh(a1);
    }
    __syncthreads();

    if (tid < 20) {
      float a2 = b2[tid];
      for (int k = 0; k < 64; ++k) a2 = fmaf(h2[k], W2[k * 20 + tid], a2);
      out[head * (BATCH * 20) + b * 20 + tid] = a2;
    }
    __syncthreads();
  }
}

extern "C" void kernel_launch(void* const* d_in, const int* in_sizes, int n_in,
                              void* d_out, int out_size, void* d_ws, size_t ws_size,
                              hipStream_t stream) {
  const float* y     = (const float*)d_in[0];
  const float* u     = (const float*)d_in[1];
  const float* Wi_f  = (const float*)d_in[2];
  const float* bi_f  = (const float*)d_in[3];
  const float* Wh_f  = (const float*)d_in[4];
  const float* bhn_f = (const float*)d_in[5];
  const float* Wi_b  = (const float*)d_in[6];
  const float* bi_b  = (const float*)d_in[7];
  const float* Wh_b  = (const float*)d_in[8];
  const float* bhn_b = (const float*)d_in[9];
  const float* mW0 = (const float*)d_in[10]; const float* mb0 = (const float*)d_in[11];
  const float* mW1 = (const float*)d_in[12]; const float* mb1 = (const float*)d_in[13];
  const float* mW2 = (const float*)d_in[14]; const float* mb2 = (const float*)d_in[15];
  const float* sW0 = (const float*)d_in[16]; const float* sb0 = (const float*)d_in[17];
  const float* sW1 = (const float*)d_in[18]; const float* sb1 = (const float*)d_in[19];
  const float* sW2 = (const float*)d_in[20]; const float* sb2 = (const float*)d_in[21];

  float* feat = (float*)d_ws;  // [64, 256]
  float* out  = (float*)d_out; // m[64,20] then s[64,20]

  gru_scan_kernel<<<BATCH * 2, NT, 0, stream>>>(
      y, u, Wi_f, bi_f, Wh_f, bhn_f, Wi_b, bi_b, Wh_b, bhn_b, feat);
  mlp_kernel<<<BATCH, 128, 0, stream>>>(
      feat, mW0, mb0, mW1, mb1, mW2, mb2, sW0, sb0, sW1, sb1, sW2, sb2, out);
}